// Round 12
// baseline (116.086 us; speedup 1.0000x reference)
//
#include <hip/hip_runtime.h>

#define SEQ  2048
#define DH   64
#define QBLK 128         // q rows per q-block
#define KBLK 64          // k/v rows per staged tile
#define NQB  (SEQ/QBLK)  // 16
#define NTIL (SEQ/KBLK)  // 32 tiles per bh
#define THR  11.5f       // defer-max threshold (log2 domain)
#define KPAT(r) ((((r)&3)) + 8*((r)>>2))   // 32x32 C/D row pattern
#define WS_NEEDED ((size_t)2 * 64 * SEQ * DH * 2)   // K+V bf16 images = 33.5 MB

typedef short bf16x8 __attribute__((ext_vector_type(8)));   // 8 bf16 bits = 4 VGPRs
typedef float f32x16 __attribute__((ext_vector_type(16)));

union V4U { unsigned int w[4]; bf16x8 v; };

__device__ __forceinline__ short bfbits(float f) {
    unsigned int u = __float_as_uint(f);
    u += 0x7fff + ((u >> 16) & 1);
    return (short)(u >> 16);
}
__device__ __forceinline__ unsigned int cvtpk(float lo, float hi) {
    unsigned int r;
    asm("v_cvt_pk_bf16_f32 %0, %1, %2" : "=v"(r) : "v"(lo), "v"(hi));
    return r;
}
// swizzled short-index into a [rows][64] bf16 tile (row stride 128 B)
__device__ __forceinline__ int swz(int row, int col) {
    return row * 64 + (col ^ ((row & 7) << 3));
}
// async global->LDS, 16B per lane; LDS dest = uniform base + lane*16
__device__ __forceinline__ void gload16(const void* g, void* l) {
    __builtin_amdgcn_global_load_lds(
        (const __attribute__((address_space(1))) unsigned int*)g,
        (__attribute__((address_space(3))) unsigned int*)l,
        16, 0, 0);
}

// ================= pre-pass: K/V -> bf16 swizzled tile images =================
__global__ __launch_bounds__(256) void prep_kv(const float* __restrict__ Kg,
                                               const float* __restrict__ Vg,
                                               short* __restrict__ Kimg,
                                               short* __restrict__ Vimg) {
    __shared__ __align__(16) short Vt[64 * 64];
    const int tid = threadIdx.x;
    const int t   = blockIdx.x & (NTIL - 1);
    const int bh  = blockIdx.x / NTIL;
    const int kb  = t * KBLK;

    const float* Kb = Kg + (size_t)bh * SEQ * DH;
    const float* Vb = Vg + (size_t)bh * SEQ * DH;
    short* kim = Kimg + ((size_t)bh * NTIL + t) * 4096;
    short* vim = Vimg + ((size_t)bh * NTIL + t) * 4096;

    {
        const int kr = tid >> 2, sd0 = (tid & 3) * 16;
        const float* src = Kb + (size_t)(kb + kr) * DH + sd0;
        const float4 a0 = *reinterpret_cast<const float4*>(src);
        const float4 a1 = *reinterpret_cast<const float4*>(src + 4);
        const float4 a2 = *reinterpret_cast<const float4*>(src + 8);
        const float4 a3 = *reinterpret_cast<const float4*>(src + 12);
        V4U u0, u1;
        u0.w[0] = cvtpk(a0.x, a0.y); u0.w[1] = cvtpk(a0.z, a0.w);
        u0.w[2] = cvtpk(a1.x, a1.y); u0.w[3] = cvtpk(a1.z, a1.w);
        u1.w[0] = cvtpk(a2.x, a2.y); u1.w[1] = cvtpk(a2.z, a2.w);
        u1.w[2] = cvtpk(a3.x, a3.y); u1.w[3] = cvtpk(a3.z, a3.w);
        *reinterpret_cast<bf16x8*>(&kim[swz(kr, sd0)])     = u0.v;
        *reinterpret_cast<bf16x8*>(&kim[swz(kr, sd0 + 8)]) = u1.v;
    }
    {
        const int vk = tid & 63, vd0 = (tid >> 6) * 16;
        const float* src = Vb + (size_t)(kb + vk) * DH + vd0;
        const float4 b0 = *reinterpret_cast<const float4*>(src);
        const float4 b1 = *reinterpret_cast<const float4*>(src + 4);
        const float4 b2 = *reinterpret_cast<const float4*>(src + 8);
        const float4 b3 = *reinterpret_cast<const float4*>(src + 12);
        const float vv[16] = {b0.x,b0.y,b0.z,b0.w, b1.x,b1.y,b1.z,b1.w,
                              b2.x,b2.y,b2.z,b2.w, b3.x,b3.y,b3.z,b3.w};
        #pragma unroll
        for (int i = 0; i < 16; ++i)
            Vt[swz(vd0 + i, vk)] = bfbits(vv[i]);
    }
    __syncthreads();
    *reinterpret_cast<bf16x8*>(&vim[tid * 16])     = *reinterpret_cast<const bf16x8*>(&Vt[tid * 16]);
    *reinterpret_cast<bf16x8*>(&vim[tid * 16 + 8]) = *reinterpret_cast<const bf16x8*>(&Vt[tid * 16 + 8]);
}

// ================= shared helpers =================
__device__ __forceinline__ void load_qfrags(const float* Qb, int q, int h, float SC,
                                            bf16x8 (&qb)[4]) {
    const float* qp = Qb + (size_t)q * DH + h * 8;
    #pragma unroll
    for (int dc = 0; dc < 4; ++dc) {
        const float4 a = *reinterpret_cast<const float4*>(qp + dc * 16);
        const float4 b = *reinterpret_cast<const float4*>(qp + dc * 16 + 4);
        V4U u;
        u.w[0] = cvtpk(a.x * SC, a.y * SC);
        u.w[1] = cvtpk(a.z * SC, a.w * SC);
        u.w[2] = cvtpk(b.x * SC, b.y * SC);
        u.w[3] = cvtpk(b.z * SC, b.w * SC);
        qb[dc] = u.v;
    }
}

// QK^T for one 32-row k-sub-block, kf loaded with tight lifetime
__device__ __forceinline__ f32x16 qk32(const short* __restrict__ Ksb, int row, int ql, int h,
                                       const bf16x8 (&qb)[4]) {
    f32x16 s;
    #pragma unroll
    for (int i = 0; i < 16; ++i) s[i] = 0.f;
    bf16x8 kf[4];
    #pragma unroll
    for (int dc = 0; dc < 4; ++dc)
        kf[dc] = *reinterpret_cast<const bf16x8*>(&Ksb[swz(row + ql, dc * 16 + h * 8)]);
    __builtin_amdgcn_s_setprio(1);
    #pragma unroll
    for (int dc = 0; dc < 4; ++dc)
        s = __builtin_amdgcn_mfma_f32_32x32x16_bf16(kf[dc], qb[dc], s, 0, 0, 0);
    __builtin_amdgcn_s_setprio(0);
    return s;
}

// mask + defer-max + exp(in-place) + pack into PV A-frags (per-wave, one q-block)
__device__ __forceinline__ void sm_pack(f32x16& s0, f32x16& s1, bool v2,
                                        int kb, int qw, int q, int h,
                                        float& m, float& lsum,
                                        f32x16& o0, f32x16& o1, bf16x8 (&pa)[4]) {
    if (kb + 31 > qw) {
        #pragma unroll
        for (int r = 0; r < 16; ++r)
            if (kb + KPAT(r) + 4 * h > q) s0[r] = -1e30f;
    }
    if (v2 && (kb + 63 > qw)) {
        #pragma unroll
        for (int r = 0; r < 16; ++r)
            if (kb + 32 + KPAT(r) + 4 * h > q) s1[r] = -1e30f;
    }
    float mx = s0[0];
    #pragma unroll
    for (int r = 1; r < 16; ++r) mx = fmaxf(mx, s0[r]);
    if (v2) {
        #pragma unroll
        for (int r = 0; r < 16; ++r) mx = fmaxf(mx, s1[r]);
    }
    if (!__all(mx <= m + THR)) {
        mx = fmaxf(mx, __shfl_xor(mx, 32));
        const float mn  = fmaxf(m, mx);
        const float scl = __builtin_amdgcn_exp2f(m - mn);
        m = mn;
        lsum *= scl;
        #pragma unroll
        for (int r = 0; r < 16; ++r) {
            const float sr = __shfl(scl, KPAT(r) + 4 * h);
            o0[r] *= sr; o1[r] *= sr;
        }
    }
    #pragma unroll
    for (int r = 0; r < 16; ++r) { s0[r] = __builtin_amdgcn_exp2f(s0[r] - m); lsum += s0[r]; }
    #pragma unroll
    for (int oct = 0; oct < 2; ++oct) {
        const unsigned int A0 = cvtpk(s0[oct*8+0], s0[oct*8+1]);
        const unsigned int A1 = cvtpk(s0[oct*8+2], s0[oct*8+3]);
        const unsigned int B0 = cvtpk(s0[oct*8+4], s0[oct*8+5]);
        const unsigned int B1 = cvtpk(s0[oct*8+6], s0[oct*8+7]);
        const unsigned int t0 = h ? A0 : B0, t1 = h ? A1 : B1;
        const unsigned int r0 = (unsigned int)__shfl_xor((int)t0, 32);
        const unsigned int r1 = (unsigned int)__shfl_xor((int)t1, 32);
        V4U u;
        u.w[0] = h ? r0 : A0; u.w[1] = h ? r1 : A1;
        u.w[2] = h ? B0 : r0; u.w[3] = h ? B1 : r1;
        pa[oct] = u.v;
    }
    if (v2) {
        #pragma unroll
        for (int r = 0; r < 16; ++r) { s1[r] = __builtin_amdgcn_exp2f(s1[r] - m); lsum += s1[r]; }
        #pragma unroll
        for (int oct = 0; oct < 2; ++oct) {
            const unsigned int A0 = cvtpk(s1[oct*8+0], s1[oct*8+1]);
            const unsigned int A1 = cvtpk(s1[oct*8+2], s1[oct*8+3]);
            const unsigned int B0 = cvtpk(s1[oct*8+4], s1[oct*8+5]);
            const unsigned int B1 = cvtpk(s1[oct*8+6], s1[oct*8+7]);
            const unsigned int t0 = h ? A0 : B0, t1 = h ? A1 : B1;
            const unsigned int r0 = (unsigned int)__shfl_xor((int)t0, 32);
            const unsigned int r1 = (unsigned int)__shfl_xor((int)t1, 32);
            V4U u;
            u.w[0] = h ? r0 : A0; u.w[1] = h ? r1 : A1;
            u.w[2] = h ? B0 : r0; u.w[3] = h ? B1 : r1;
            pa[2 + oct] = u.v;
        }
    }
}

// PV for one output half (d-row = drow+ql), vf loaded per-MFMA with tight lifetime
__device__ __forceinline__ void pv_half(const short* __restrict__ Vtb, int drow, int ql, int h,
                                        const bf16x8 (&pa)[4], f32x16& o, bool v2) {
    __builtin_amdgcn_s_setprio(1);
    #pragma unroll
    for (int kt = 0; kt < 2; ++kt) {
        const bf16x8 vf = *reinterpret_cast<const bf16x8*>(&Vtb[swz(drow + ql, kt * 16 + h * 8)]);
        o = __builtin_amdgcn_mfma_f32_32x32x16_bf16(pa[kt], vf, o, 0, 0, 0);
    }
    if (v2) {
        #pragma unroll
        for (int kt = 2; kt < 4; ++kt) {
            const bf16x8 vf = *reinterpret_cast<const bf16x8*>(&Vtb[swz(drow + ql, kt * 16 + h * 8)]);
            o = __builtin_amdgcn_mfma_f32_32x32x16_bf16(pa[kt], vf, o, 0, 0, 0);
        }
    }
    __builtin_amdgcn_s_setprio(0);
}

__device__ __forceinline__ void epilogue_store(float* Ob, int qw, int h, int ql,
                                               const f32x16& o0, const f32x16& o1,
                                               float lsum) {
    lsum += __shfl_xor(lsum, 32);
    const float inv = 1.0f / lsum;
    #pragma unroll
    for (int r = 0; r < 16; ++r) {
        const float ir  = __shfl(inv, KPAT(r) + 4 * h);
        const size_t row = (size_t)(qw + KPAT(r) + 4 * h);
        Ob[row * DH + ql]      = o0[r] * ir;
        Ob[row * DH + 32 + ql] = o1[r] * ir;
    }
}

// ================= main kernel: 512 threads, pair split across wave halves =================
// Each lane stages 16B of K and 16B of V per tile (512 lanes cover the 8KB tile).
#define STAGE(b_, t_) do {                                                   \
    const short* kim_ = kimg + (size_t)(t_) * 4096 + w * 512 + lane * 8;     \
    const short* vim_ = vimg + (size_t)(t_) * 4096 + w * 512 + lane * 8;     \
    gload16(kim_, &Ks[b_][w * 512]);                                         \
    gload16(vim_, &Vt[b_][w * 512]);                                         \
} while (0)

__global__ __launch_bounds__(512, 2) void attn_fwd(const float* __restrict__ Qg,
                                                   const short* __restrict__ Kimg,
                                                   const short* __restrict__ Vimg,
                                                   float* __restrict__ Og) {
    __shared__ __align__(16) short Ks[3][64 * 64];   // K tiles, swizzled, tri-buffer
    __shared__ __align__(16) short Vt[3][64 * 64];   // V tiles, swizzled, tri-buffer

    const int tid  = threadIdx.x;
    const int w    = tid >> 6;       // wave 0..7
    const int lane = tid & 63;
    const int h    = lane >> 5;
    const int ql   = lane & 31;
    const int wq   = w & 3;          // sub-row within q-block
    const int isB  = w >> 2;         // wave-half: 0 -> q-block A, 1 -> q-block B

    // pair selection, de-aliased from XCD (XCD = bid%8; pp = (j+bh)&7 so each
    // XCD sees all pair lengths uniformly -- j alone would pin pp==XCD).
    const int j   = blockIdx.x & 7;
    const int bh  = blockIdx.x >> 3;
    const int pp  = (j + bh) & 7;
    const int qblkA = pp, qblkB = NQB - 1 - pp;
    const int qblk  = isB ? qblkB : qblkA;

    const float* Qb   = Qg + (size_t)bh * SEQ * DH;
    const short* kimg = Kimg + (size_t)bh * NTIL * 4096;
    const short* vimg = Vimg + (size_t)bh * NTIL * 4096;
    float*       Ob   = Og + (size_t)bh * SEQ * DH;

    const float SC = 0.125f * 1.44269504f;   // 1/sqrt(64) * log2(e)

    const int qw   = qblk * QBLK + wq * 32;  // this wave's 32 q-rows
    const int q    = qw + ql;
    const int kend = qw + 32;                // causal k limit (exclusive)
    const int nt   = qblkB * 2 + 2;          // block-uniform iteration count

    STAGE(0, 0);
    STAGE(1, 1);

    bf16x8 qb[4];
    load_qfrags(Qb, q, h, SC, qb);

    f32x16 o0, o1;
    #pragma unroll
    for (int i = 0; i < 16; ++i) { o0[i] = 0.f; o1[i] = 0.f; }
    float m = -1e30f, lsum = 0.f;

    __syncthreads();                  // tiles 0,1 resident

    for (int t = 0; t < nt; ++t) {
        const int kb  = t * KBLK;
        const int cur = t % 3;

        // counted vmcnt: this wave issued 2 loads/tile; keep tile t+1's 2 in
        // flight across the barrier (T3/T4), drain only tile t's.
        if (t + 1 < nt) asm volatile("s_waitcnt vmcnt(2)" ::: "memory");
        else            asm volatile("s_waitcnt vmcnt(0)" ::: "memory");
        __builtin_amdgcn_s_barrier();

        if (t + 2 < nt) STAGE((t + 2) % 3, t + 2);

        if (kb < kend) {              // wave-uniform causal skip
            const bool v2 = (kb + 32 < kend);
            const short* Ksb = &Ks[cur][0];
            const short* Vtb = &Vt[cur][0];

            f32x16 s0 = qk32(Ksb, 0, ql, h, qb);
            f32x16 s1;
            if (v2) s1 = qk32(Ksb, 32, ql, h, qb);

            bf16x8 pa[4];
            sm_pack(s0, s1, v2, kb, qw, q, h, m, lsum, o0, o1, pa);

            pv_half(Vtb, 0,  ql, h, pa, o0, v2);
            pv_half(Vtb, 32, ql, h, pa, o1, v2);
        }
    }

    epilogue_store(Ob, qw, h, ql, o0, o1, lsum);
}

// ================= fallback (reg-staged, used if ws too small) =================
#define LOAD_STAGE(kb_) do {                                               \
    const float* ksrc = Kb + (size_t)((kb_) + skr) * DH + sd0;             \
    kr0 = *reinterpret_cast<const float4*>(ksrc);                          \
    kr1 = *reinterpret_cast<const float4*>(ksrc + 4);                      \
    kr2 = *reinterpret_cast<const float4*>(ksrc + 8);                      \
    kr3 = *reinterpret_cast<const float4*>(ksrc + 12);                     \
    const float* vsrc = Vb + (size_t)((kb_) + svk) * DH + svd0;            \
    vr0 = *reinterpret_cast<const float4*>(vsrc);                          \
    vr1 = *reinterpret_cast<const float4*>(vsrc + 4);                      \
    vr2 = *reinterpret_cast<const float4*>(vsrc + 8);                      \
    vr3 = *reinterpret_cast<const float4*>(vsrc + 12);                     \
} while (0)

#define CVT_WRITE(b_) do {                                                 \
    V4U u0, u1;                                                            \
    u0.w[0] = cvtpk(kr0.x, kr0.y); u0.w[1] = cvtpk(kr0.z, kr0.w);          \
    u0.w[2] = cvtpk(kr1.x, kr1.y); u0.w[3] = cvtpk(kr1.z, kr1.w);          \
    u1.w[0] = cvtpk(kr2.x, kr2.y); u1.w[1] = cvtpk(kr2.z, kr2.w);          \
    u1.w[2] = cvtpk(kr3.x, kr3.y); u1.w[3] = cvtpk(kr3.z, kr3.w);          \
    *reinterpret_cast<bf16x8*>(&Ks[b_][swz(skr, sd0)])     = u0.v;         \
    *reinterpret_cast<bf16x8*>(&Ks[b_][swz(skr, sd0 + 8)]) = u1.v;         \
    const float vv[16] = {vr0.x,vr0.y,vr0.z,vr0.w, vr1.x,vr1.y,vr1.z,vr1.w,\
                          vr2.x,vr2.y,vr2.z,vr2.w, vr3.x,vr3.y,vr3.z,vr3.w};\
    _Pragma("unroll")                                                      \
    for (int i_ = 0; i_ < 16; ++i_)                                        \
        Vt[b_][swz(svd0 + i_, svk)] = bfbits(vv[i_]);                      \
} while (0)

__global__ __launch_bounds__(256) void attn_fwd_fb(const float* __restrict__ Qg,
                                                   const float* __restrict__ Kg,
                                                   const float* __restrict__ Vg,
                                                   float* __restrict__ Og) {
    __shared__ __align__(16) short Ks[2][64 * 64];
    __shared__ __align__(16) short Vt[2][64 * 64];

    const int tid  = threadIdx.x;
    const int w    = tid >> 6;
    const int lane = tid & 63;
    const int h    = lane >> 5;
    const int ql   = lane & 31;

    const int j    = blockIdx.x & (NQB - 1);
    const int bh   = blockIdx.x / NQB;
    const int qblk = ((bh >> 4) & 1) ? (NQB - 1 - j) : j;
    const int q0   = qblk * QBLK;
    const int qw   = q0 + w * 32;
    const int q    = qw + ql;

    const float* Qb = Qg + (size_t)bh * SEQ * DH;
    const float* Kb = Kg + (size_t)bh * SEQ * DH;
    const float* Vb = Vg + (size_t)bh * SEQ * DH;
    float*       Ob = Og + (size_t)bh * SEQ * DH;

    const float SC = 0.125f * 1.44269504f;

    const int skr  = tid >> 2;
    const int sd0  = (tid & 3) * 16;
    const int svk  = tid & 63;
    const int svd0 = (tid >> 6) * 16;

    float4 kr0, kr1, kr2, kr3, vr0, vr1, vr2, vr3;
    LOAD_STAGE(0);

    bf16x8 qb[4];
    load_qfrags(Qb, q, h, SC, qb);

    f32x16 o0, o1;
    #pragma unroll
    for (int i = 0; i < 16; ++i) { o0[i] = 0.f; o1[i] = 0.f; }
    float m = -1e30f, lsum = 0.f;

    CVT_WRITE(0);
    __syncthreads();

    const int kend = qw + 32;
    const int nt   = (q0 + QBLK) / KBLK;

    for (int t = 0; t < nt; ++t) {
        const int kb  = t * KBLK;
        const int cur = t & 1;
        if (t + 1 < nt) LOAD_STAGE(kb + KBLK);

        if (kb < kend) {
            const bool v2 = (kb + 32 < kend);
            f32x16 s0 = qk32(&Ks[cur][0], 0, ql, h, qb);
            f32x16 s1;
            if (v2) s1 = qk32(&Ks[cur][0], 32, ql, h, qb);
            bf16x8 pa[4];
            sm_pack(s0, s1, v2, kb, qw, q, h, m, lsum, o0, o1, pa);
            pv_half(&Vt[cur][0], 0,  ql, h, pa, o0, v2);
            pv_half(&Vt[cur][0], 32, ql, h, pa, o1, v2);
        }
        if (t + 1 < nt) CVT_WRITE(cur ^ 1);
        __syncthreads();
    }

    epilogue_store(Ob, qw, h, ql, o0, o1, lsum);
}

extern "C" void kernel_launch(void* const* d_in, const int* in_sizes, int n_in,
                              void* d_out, int out_size, void* d_ws, size_t ws_size,
                              hipStream_t stream) {
    const float* Q = (const float*)d_in[0];
    const float* K = (const float*)d_in[1];
    const float* V = (const float*)d_in[2];
    // d_in[3] causal mask: synthesized in-kernel, not read.
    float* O = (float*)d_out;

    if (ws_size >= WS_NEEDED) {
        short* Kimg = (short*)d_ws;
        short* Vimg = Kimg + (size_t)64 * NTIL * 4096;
        prep_kv<<<dim3(64 * NTIL), 256, 0, stream>>>(K, V, Kimg, Vimg);
        attn_fwd<<<dim3(64 * (NQB / 2)), 512, 0, stream>>>(Q, Kimg, Vimg, O);
    } else {
        attn_fwd_fb<<<dim3(64 * NQB), 256, 0, stream>>>(Q, K, V, O);
    }
}

// Round 13
// 98.955 us; speedup vs baseline: 1.1731x; 1.1731x over previous
//
#include <hip/hip_runtime.h>

#define SEQ  2048
#define DH   64
#define QBLK 128         // q rows per q-block = 4 waves x 32
#define KBLK 64          // k/v rows per staged tile
#define NQB  (SEQ/QBLK)  // 16
#define NTIL (SEQ/KBLK)  // 32 tiles per bh
#define THR  11.5f       // defer-max threshold (log2 domain)
#define KPAT(r) ((((r)&3)) + 8*((r)>>2))   // 32x32 C/D row pattern
#define WS_NEEDED ((size_t)2 * 64 * SEQ * DH * 2)   // K+V bf16 images = 33.5 MB

typedef short bf16x8 __attribute__((ext_vector_type(8)));   // 8 bf16 bits = 4 VGPRs
typedef float f32x16 __attribute__((ext_vector_type(16)));

union V4U { unsigned int w[4]; bf16x8 v; };

__device__ __forceinline__ short bfbits(float f) {
    unsigned int u = __float_as_uint(f);
    u += 0x7fff + ((u >> 16) & 1);
    return (short)(u >> 16);
}
__device__ __forceinline__ unsigned int cvtpk(float lo, float hi) {
    unsigned int r;
    asm("v_cvt_pk_bf16_f32 %0, %1, %2" : "=v"(r) : "v"(lo), "v"(hi));
    return r;
}
// swizzled short-index into a [rows][64] bf16 tile (row stride 128 B)
__device__ __forceinline__ int swz(int row, int col) {
    return row * 64 + (col ^ ((row & 7) << 3));
}
// async global->LDS, 16B per lane; LDS dest = uniform base + lane*16
__device__ __forceinline__ void gload16(const void* g, void* l) {
    __builtin_amdgcn_global_load_lds(
        (const __attribute__((address_space(1))) unsigned int*)g,
        (__attribute__((address_space(3))) unsigned int*)l,
        16, 0, 0);
}

// ================= pre-pass: K/V -> bf16 swizzled tile images =================
__global__ __launch_bounds__(256) void prep_kv(const float* __restrict__ Kg,
                                               const float* __restrict__ Vg,
                                               short* __restrict__ Kimg,
                                               short* __restrict__ Vimg) {
    __shared__ __align__(16) short Vt[64 * 64];
    const int tid = threadIdx.x;
    const int t   = blockIdx.x & (NTIL - 1);
    const int bh  = blockIdx.x / NTIL;
    const int kb  = t * KBLK;

    const float* Kb = Kg + (size_t)bh * SEQ * DH;
    const float* Vb = Vg + (size_t)bh * SEQ * DH;
    short* kim = Kimg + ((size_t)bh * NTIL + t) * 4096;
    short* vim = Vimg + ((size_t)bh * NTIL + t) * 4096;

    {
        const int kr = tid >> 2, sd0 = (tid & 3) * 16;
        const float* src = Kb + (size_t)(kb + kr) * DH + sd0;
        const float4 a0 = *reinterpret_cast<const float4*>(src);
        const float4 a1 = *reinterpret_cast<const float4*>(src + 4);
        const float4 a2 = *reinterpret_cast<const float4*>(src + 8);
        const float4 a3 = *reinterpret_cast<const float4*>(src + 12);
        V4U u0, u1;
        u0.w[0] = cvtpk(a0.x, a0.y); u0.w[1] = cvtpk(a0.z, a0.w);
        u0.w[2] = cvtpk(a1.x, a1.y); u0.w[3] = cvtpk(a1.z, a1.w);
        u1.w[0] = cvtpk(a2.x, a2.y); u1.w[1] = cvtpk(a2.z, a2.w);
        u1.w[2] = cvtpk(a3.x, a3.y); u1.w[3] = cvtpk(a3.z, a3.w);
        *reinterpret_cast<bf16x8*>(&kim[swz(kr, sd0)])     = u0.v;
        *reinterpret_cast<bf16x8*>(&kim[swz(kr, sd0 + 8)]) = u1.v;
    }
    {
        const int vk = tid & 63, vd0 = (tid >> 6) * 16;
        const float* src = Vb + (size_t)(kb + vk) * DH + vd0;
        const float4 b0 = *reinterpret_cast<const float4*>(src);
        const float4 b1 = *reinterpret_cast<const float4*>(src + 4);
        const float4 b2 = *reinterpret_cast<const float4*>(src + 8);
        const float4 b3 = *reinterpret_cast<const float4*>(src + 12);
        const float vv[16] = {b0.x,b0.y,b0.z,b0.w, b1.x,b1.y,b1.z,b1.w,
                              b2.x,b2.y,b2.z,b2.w, b3.x,b3.y,b3.z,b3.w};
        #pragma unroll
        for (int i = 0; i < 16; ++i)
            Vt[swz(vd0 + i, vk)] = bfbits(vv[i]);
    }
    __syncthreads();
    *reinterpret_cast<bf16x8*>(&vim[tid * 16])     = *reinterpret_cast<const bf16x8*>(&Vt[tid * 16]);
    *reinterpret_cast<bf16x8*>(&vim[tid * 16 + 8]) = *reinterpret_cast<const bf16x8*>(&Vt[tid * 16 + 8]);
}

// ================= phase helpers (shared-fragment form) =================
__device__ __forceinline__ void load_kf8(const short* __restrict__ Ksb, int ql, int h,
                                         bf16x8 (&kf)[8]) {
    #pragma unroll
    for (int dc = 0; dc < 4; ++dc) {
        kf[dc]     = *reinterpret_cast<const bf16x8*>(&Ksb[swz(ql,      dc * 16 + h * 8)]);
        kf[4 + dc] = *reinterpret_cast<const bf16x8*>(&Ksb[swz(32 + ql, dc * 16 + h * 8)]);
    }
}
__device__ __forceinline__ void load_vf8(const short* __restrict__ Vtb, int ql, int h,
                                         bf16x8 (&vf)[8]) {
    #pragma unroll
    for (int kt = 0; kt < 4; ++kt) {
        vf[kt]     = *reinterpret_cast<const bf16x8*>(&Vtb[swz(ql,      kt * 16 + h * 8)]);
        vf[4 + kt] = *reinterpret_cast<const bf16x8*>(&Vtb[swz(32 + ql, kt * 16 + h * 8)]);
    }
}
__device__ __forceinline__ void qk_phase(const bf16x8 (&kf)[8], const bf16x8 (&qb)[4],
                                         f32x16& s0, f32x16& s1, bool v2) {
    #pragma unroll
    for (int i = 0; i < 16; ++i) s0[i] = 0.f;
    __builtin_amdgcn_s_setprio(1);
    #pragma unroll
    for (int dc = 0; dc < 4; ++dc)
        s0 = __builtin_amdgcn_mfma_f32_32x32x16_bf16(kf[dc], qb[dc], s0, 0, 0, 0);
    __builtin_amdgcn_s_setprio(0);
    if (v2) {
        #pragma unroll
        for (int i = 0; i < 16; ++i) s1[i] = 0.f;
        __builtin_amdgcn_s_setprio(1);
        #pragma unroll
        for (int dc = 0; dc < 4; ++dc)
            s1 = __builtin_amdgcn_mfma_f32_32x32x16_bf16(kf[4 + dc], qb[dc], s1, 0, 0, 0);
        __builtin_amdgcn_s_setprio(0);
    }
}
// mask + defer-max + exp(in-place) + pack into PV A-frags.
// Row-max and row-sum are TREE reductions (dep depth ~5) -- the old serial
// 31/32-deep fmax/add chains were ~400 cy of unoverlappable latency per iter.
__device__ __forceinline__ void sm_pack(f32x16& s0, f32x16& s1, bool v2,
                                        int kb, int qw, int q, int h,
                                        float& m, float& lsum,
                                        f32x16& o0, f32x16& o1, bf16x8 (&pa)[4]) {
    if (kb + 31 > qw) {
        #pragma unroll
        for (int r = 0; r < 16; ++r)
            if (kb + KPAT(r) + 4 * h > q) s0[r] = -1e30f;
    }
    if (v2 && (kb + 63 > qw)) {
        #pragma unroll
        for (int r = 0; r < 16; ++r)
            if (kb + 32 + KPAT(r) + 4 * h > q) s1[r] = -1e30f;
    }
    // ---- tree row-max ----
    float t8[8];
    #pragma unroll
    for (int i = 0; i < 8; ++i) t8[i] = fmaxf(s0[i], s0[i + 8]);
    if (v2) {
        #pragma unroll
        for (int i = 0; i < 8; ++i) t8[i] = fmaxf(t8[i], fmaxf(s1[i], s1[i + 8]));
    }
    const float t40 = fmaxf(t8[0], t8[4]), t41 = fmaxf(t8[1], t8[5]);
    const float t42 = fmaxf(t8[2], t8[6]), t43 = fmaxf(t8[3], t8[7]);
    float mx = fmaxf(fmaxf(t40, t41), fmaxf(t42, t43));

    if (!__all(mx <= m + THR)) {
        mx = fmaxf(mx, __shfl_xor(mx, 32));
        const float mn  = fmaxf(m, mx);
        const float scl = __builtin_amdgcn_exp2f(m - mn);
        m = mn;
        lsum *= scl;
        #pragma unroll
        for (int r = 0; r < 16; ++r) {
            const float sr = __shfl(scl, KPAT(r) + 4 * h);
            o0[r] *= sr; o1[r] *= sr;
        }
    }
    // ---- exp (independent, pipelined) ----
    #pragma unroll
    for (int r = 0; r < 16; ++r) s0[r] = __builtin_amdgcn_exp2f(s0[r] - m);
    if (v2) {
        #pragma unroll
        for (int r = 0; r < 16; ++r) s1[r] = __builtin_amdgcn_exp2f(s1[r] - m);
    }
    // ---- tree row-sum ----
    {
        float a8[8];
        #pragma unroll
        for (int i = 0; i < 8; ++i) a8[i] = s0[i] + s0[i + 8];
        if (v2) {
            #pragma unroll
            for (int i = 0; i < 8; ++i) a8[i] += s1[i] + s1[i + 8];
        }
        const float a40 = a8[0] + a8[4], a41 = a8[1] + a8[5];
        const float a42 = a8[2] + a8[6], a43 = a8[3] + a8[7];
        lsum += (a40 + a41) + (a42 + a43);
    }
    // ---- pack into PV A-frags (cvt_pk + half-exchange) ----
    #pragma unroll
    for (int oct = 0; oct < 2; ++oct) {
        const unsigned int A0 = cvtpk(s0[oct*8+0], s0[oct*8+1]);
        const unsigned int A1 = cvtpk(s0[oct*8+2], s0[oct*8+3]);
        const unsigned int B0 = cvtpk(s0[oct*8+4], s0[oct*8+5]);
        const unsigned int B1 = cvtpk(s0[oct*8+6], s0[oct*8+7]);
        const unsigned int t0 = h ? A0 : B0, t1 = h ? A1 : B1;
        const unsigned int r0 = (unsigned int)__shfl_xor((int)t0, 32);
        const unsigned int r1 = (unsigned int)__shfl_xor((int)t1, 32);
        V4U u;
        u.w[0] = h ? r0 : A0; u.w[1] = h ? r1 : A1;
        u.w[2] = h ? B0 : r0; u.w[3] = h ? B1 : r1;
        pa[oct] = u.v;
    }
    if (v2) {
        #pragma unroll
        for (int oct = 0; oct < 2; ++oct) {
            const unsigned int A0 = cvtpk(s1[oct*8+0], s1[oct*8+1]);
            const unsigned int A1 = cvtpk(s1[oct*8+2], s1[oct*8+3]);
            const unsigned int B0 = cvtpk(s1[oct*8+4], s1[oct*8+5]);
            const unsigned int B1 = cvtpk(s1[oct*8+6], s1[oct*8+7]);
            const unsigned int t0 = h ? A0 : B0, t1 = h ? A1 : B1;
            const unsigned int r0 = (unsigned int)__shfl_xor((int)t0, 32);
            const unsigned int r1 = (unsigned int)__shfl_xor((int)t1, 32);
            V4U u;
            u.w[0] = h ? r0 : A0; u.w[1] = h ? r1 : A1;
            u.w[2] = h ? B0 : r0; u.w[3] = h ? B1 : r1;
            pa[2 + oct] = u.v;
        }
    }
}
__device__ __forceinline__ void pv_phase(const bf16x8 (&pa)[4], const bf16x8 (&vf)[8],
                                         f32x16& o0, f32x16& o1, bool v2) {
    __builtin_amdgcn_s_setprio(1);
    #pragma unroll
    for (int kt = 0; kt < 2; ++kt) {
        o0 = __builtin_amdgcn_mfma_f32_32x32x16_bf16(pa[kt], vf[kt],     o0, 0, 0, 0);
        o1 = __builtin_amdgcn_mfma_f32_32x32x16_bf16(pa[kt], vf[4 + kt], o1, 0, 0, 0);
    }
    if (v2) {
        #pragma unroll
        for (int kt = 2; kt < 4; ++kt) {
            o0 = __builtin_amdgcn_mfma_f32_32x32x16_bf16(pa[kt], vf[kt],     o0, 0, 0, 0);
            o1 = __builtin_amdgcn_mfma_f32_32x32x16_bf16(pa[kt], vf[4 + kt], o1, 0, 0, 0);
        }
    }
    __builtin_amdgcn_s_setprio(0);
}

__device__ __forceinline__ void load_qfrags(const float* Qb, int q, int h, float SC,
                                            bf16x8 (&qb)[4]) {
    const float* qp = Qb + (size_t)q * DH + h * 8;
    #pragma unroll
    for (int dc = 0; dc < 4; ++dc) {
        const float4 a = *reinterpret_cast<const float4*>(qp + dc * 16);
        const float4 b = *reinterpret_cast<const float4*>(qp + dc * 16 + 4);
        V4U u;
        u.w[0] = cvtpk(a.x * SC, a.y * SC);
        u.w[1] = cvtpk(a.z * SC, a.w * SC);
        u.w[2] = cvtpk(b.x * SC, b.y * SC);
        u.w[3] = cvtpk(b.z * SC, b.w * SC);
        qb[dc] = u.v;
    }
}

__device__ __forceinline__ void epilogue_store(float* Ob, int qw, int h, int ql,
                                               const f32x16& o0, const f32x16& o1,
                                               float lsum) {
    lsum += __shfl_xor(lsum, 32);
    const float inv = 1.0f / lsum;
    #pragma unroll
    for (int r = 0; r < 16; ++r) {
        const float ir  = __shfl(inv, KPAT(r) + 4 * h);
        const size_t row = (size_t)(qw + KPAT(r) + 4 * h);
        Ob[row * DH + ql]      = o0[r] * ir;
        Ob[row * DH + 32 + ql] = o1[r] * ir;
    }
}

// ================= main kernel: paired q-blocks, shared K/V fragments =================
#define STAGE(b_, t_) do {                                                   \
    const short* kim_ = kimg + (size_t)(t_) * 4096 + w * 1024 + lane * 8;    \
    const short* vim_ = vimg + (size_t)(t_) * 4096 + w * 1024 + lane * 8;    \
    gload16(kim_,       &Ks[b_][w * 1024]);                                  \
    gload16(kim_ + 512, &Ks[b_][w * 1024 + 512]);                            \
    gload16(vim_,       &Vt[b_][w * 1024]);                                  \
    gload16(vim_ + 512, &Vt[b_][w * 1024 + 512]);                            \
} while (0)

__global__ __launch_bounds__(256, 2) void attn_fwd(const float* __restrict__ Qg,
                                                   const short* __restrict__ Kimg,
                                                   const short* __restrict__ Vimg,
                                                   float* __restrict__ Og) {
    __shared__ __align__(16) short Ks[3][64 * 64];   // K tiles, swizzled, tri-buffer
    __shared__ __align__(16) short Vt[3][64 * 64];   // V tiles, swizzled, tri-buffer

    const int tid  = threadIdx.x;
    const int w    = tid >> 6;
    const int lane = tid & 63;
    const int h    = lane >> 5;
    const int ql   = lane & 31;

    // paired q-blocks, DE-ALIASED from XCD: XCD = bid%8; with pp = bid&7 every
    // XCD would get a single pair length (XCD0 always nt=32, XCD7 nt=18 ->
    // 1.3-1.4x imbalance). pp=(j+bh)&7 spreads all lengths over every XCD.
    const int j   = blockIdx.x & 7;
    const int bh  = blockIdx.x >> 3;
    const int pp  = (j + bh) & 7;
    const int qblkA = pp, qblkB = NQB - 1 - pp;

    const float* Qb   = Qg + (size_t)bh * SEQ * DH;
    const short* kimg = Kimg + (size_t)bh * NTIL * 4096;
    const short* vimg = Vimg + (size_t)bh * NTIL * 4096;
    float*       Ob   = Og + (size_t)bh * SEQ * DH;

    const float SC = 0.125f * 1.44269504f;   // 1/sqrt(64) * log2(e)

    const int qwA = qblkA * QBLK + w * 32, qA = qwA + ql, kendA = qwA + 32;
    const int qwB = qblkB * QBLK + w * 32, qB = qwB + ql, kendB = qwB + 32;
    const int nt  = qblkB * 2 + 2;

    STAGE(0, 0);
    STAGE(1, 1);

    bf16x8 qbA[4], qbB[4];
    load_qfrags(Qb, qA, h, SC, qbA);
    load_qfrags(Qb, qB, h, SC, qbB);

    f32x16 oA0, oA1, oB0, oB1;
    #pragma unroll
    for (int i = 0; i < 16; ++i) { oA0[i]=0.f; oA1[i]=0.f; oB0[i]=0.f; oB1[i]=0.f; }
    float mA = -1e30f, lA = 0.f, mB = -1e30f, lB = 0.f;

    __syncthreads();                  // tiles 0,1 resident

    for (int t = 0; t < nt; ++t) {
        const int kb  = t * KBLK;
        const int cur = t % 3;

        // counted vmcnt: drain tile t's 4 loads; later tiles stay in flight (T3/T4)
        if (t + 1 < nt) asm volatile("s_waitcnt vmcnt(4)" ::: "memory");
        else            asm volatile("s_waitcnt vmcnt(0)" ::: "memory");
        __builtin_amdgcn_s_barrier();

        if (t + 2 < nt) STAGE((t + 2) % 3, t + 2);

        const short* Ksb = &Ks[cur][0];
        const short* Vtb = &Vt[cur][0];
        const bool aAct = kb < kendA;
        const bool bAct = kb < kendB;
        const bool v2A  = kb + 32 < kendA;
        const bool v2B  = kb + 32 < kendB;

        bf16x8 kf[8];
        load_kf8(Ksb, ql, h, kf);

        f32x16 sA0, sA1, sB0, sB1;
        if (aAct) qk_phase(kf, qbA, sA0, sA1, v2A);
        if (bAct) qk_phase(kf, qbB, sB0, sB1, v2B);   // MFMA busy while VALU does smA

        bf16x8 vf[8];
        load_vf8(Vtb, ql, h, vf);

        if (aAct) {
            bf16x8 paA[4];
            sm_pack(sA0, sA1, v2A, kb, qwA, qA, h, mA, lA, oA0, oA1, paA);
            pv_phase(paA, vf, oA0, oA1, v2A);
        }
        if (bAct) {
            bf16x8 paB[4];
            sm_pack(sB0, sB1, v2B, kb, qwB, qB, h, mB, lB, oB0, oB1, paB);
            pv_phase(paB, vf, oB0, oB1, v2B);
        }
    }

    epilogue_store(Ob, qwA, h, ql, oA0, oA1, lA);
    epilogue_store(Ob, qwB, h, ql, oB0, oB1, lB);
}

// ================= fallback (reg-staged, used if ws too small) =================
#define LOAD_STAGE(kb_) do {                                               \
    const float* ksrc = Kb + (size_t)((kb_) + skr) * DH + sd0;             \
    kr0 = *reinterpret_cast<const float4*>(ksrc);                          \
    kr1 = *reinterpret_cast<const float4*>(ksrc + 4);                      \
    kr2 = *reinterpret_cast<const float4*>(ksrc + 8);                      \
    kr3 = *reinterpret_cast<const float4*>(ksrc + 12);                     \
    const float* vsrc = Vb + (size_t)((kb_) + svk) * DH + svd0;            \
    vr0 = *reinterpret_cast<const float4*>(vsrc);                          \
    vr1 = *reinterpret_cast<const float4*>(vsrc + 4);                      \
    vr2 = *reinterpret_cast<const float4*>(vsrc + 8);                      \
    vr3 = *reinterpret_cast<const float4*>(vsrc + 12);                     \
} while (0)

#define CVT_WRITE(b_) do {                                                 \
    V4U u0, u1;                                                            \
    u0.w[0] = cvtpk(kr0.x, kr0.y); u0.w[1] = cvtpk(kr0.z, kr0.w);          \
    u0.w[2] = cvtpk(kr1.x, kr1.y); u0.w[3] = cvtpk(kr1.z, kr1.w);          \
    u1.w[0] = cvtpk(kr2.x, kr2.y); u1.w[1] = cvtpk(kr2.z, kr2.w);          \
    u1.w[2] = cvtpk(kr3.x, kr3.y); u1.w[3] = cvtpk(kr3.z, kr3.w);          \
    *reinterpret_cast<bf16x8*>(&Ks[b_][swz(skr, sd0)])     = u0.v;         \
    *reinterpret_cast<bf16x8*>(&Ks[b_][swz(skr, sd0 + 8)]) = u1.v;         \
    const float vv[16] = {vr0.x,vr0.y,vr0.z,vr0.w, vr1.x,vr1.y,vr1.z,vr1.w,\
                          vr2.x,vr2.y,vr2.z,vr2.w, vr3.x,vr3.y,vr3.z,vr3.w};\
    _Pragma("unroll")                                                      \
    for (int i_ = 0; i_ < 16; ++i_)                                        \
        Vt[b_][swz(svd0 + i_, svk)] = bfbits(vv[i_]);                      \
} while (0)

__global__ __launch_bounds__(256) void attn_fwd_fb(const float* __restrict__ Qg,
                                                   const float* __restrict__ Kg,
                                                   const float* __restrict__ Vg,
                                                   float* __restrict__ Og) {
    __shared__ __align__(16) short Ks[2][64 * 64];
    __shared__ __align__(16) short Vt[2][64 * 64];

    const int tid  = threadIdx.x;
    const int w    = tid >> 6;
    const int lane = tid & 63;
    const int h    = lane >> 5;
    const int ql   = lane & 31;

    const int j    = blockIdx.x & (NQB - 1);
    const int bh   = blockIdx.x / NQB;
    const int qblk = ((bh >> 4) & 1) ? (NQB - 1 - j) : j;
    const int q0   = qblk * QBLK;
    const int qw   = q0 + w * 32;
    const int q    = qw + ql;

    const float* Qb = Qg + (size_t)bh * SEQ * DH;
    const float* Kb = Kg + (size_t)bh * SEQ * DH;
    const float* Vb = Vg + (size_t)bh * SEQ * DH;
    float*       Ob = Og + (size_t)bh * SEQ * DH;

    const float SC = 0.125f * 1.44269504f;

    const int skr  = tid >> 2;
    const int sd0  = (tid & 3) * 16;
    const int svk  = tid & 63;
    const int svd0 = (tid >> 6) * 16;

    float4 kr0, kr1, kr2, kr3, vr0, vr1, vr2, vr3;
    LOAD_STAGE(0);

    bf16x8 qb[4];
    load_qfrags(Qb, q, h, SC, qb);

    f32x16 o0, o1;
    #pragma unroll
    for (int i = 0; i < 16; ++i) { o0[i] = 0.f; o1[i] = 0.f; }
    float m = -1e30f, lsum = 0.f;

    CVT_WRITE(0);
    __syncthreads();

    const int kend = qw + 32;
    const int nt   = (q0 + QBLK) / KBLK;

    for (int t = 0; t < nt; ++t) {
        const int kb  = t * KBLK;
        const int cur = t & 1;
        if (t + 1 < nt) LOAD_STAGE(kb + KBLK);

        if (kb < kend) {
            const bool v2 = (kb + 32 < kend);
            bf16x8 kf[8];
            load_kf8(&Ks[cur][0], ql, h, kf);
            f32x16 s0, s1;
            qk_phase(kf, qb, s0, s1, v2);
            bf16x8 vf[8];
            load_vf8(&Vt[cur][0], ql, h, vf);
            bf16x8 pa[4];
            sm_pack(s0, s1, v2, kb, qw, q, h, m, lsum, o0, o1, pa);
            pv_phase(pa, vf, o0, o1, v2);
        }
        if (t + 1 < nt) CVT_WRITE(cur ^ 1);
        __syncthreads();
    }

    epilogue_store(Ob, qw, h, ql, o0, o1, lsum);
}

extern "C" void kernel_launch(void* const* d_in, const int* in_sizes, int n_in,
                              void* d_out, int out_size, void* d_ws, size_t ws_size,
                              hipStream_t stream) {
    const float* Q = (const float*)d_in[0];
    const float* K = (const float*)d_in[1];
    const float* V = (const float*)d_in[2];
    // d_in[3] causal mask: synthesized in-kernel, not read.
    float* O = (float*)d_out;

    if (ws_size >= WS_NEEDED) {
        short* Kimg = (short*)d_ws;
        short* Vimg = Kimg + (size_t)64 * NTIL * 4096;
        prep_kv<<<dim3(64 * NTIL), 256, 0, stream>>>(K, V, Kimg, Vimg);
        attn_fwd<<<dim3(64 * (NQB / 2)), 256, 0, stream>>>(Q, Kimg, Vimg, O);
    } else {
        attn_fwd_fb<<<dim3(64 * NQB), 256, 0, stream>>>(Q, K, V, O);
    }
}

// Round 14
// 79.389 us; speedup vs baseline: 1.4623x; 1.2465x over previous
//
#include <hip/hip_runtime.h>

#define SEQ  2048
#define DH   64
#define QBLK 128         // q rows per q-block
#define KBLK 64          // k/v rows per tile
#define NQB  (SEQ/QBLK)  // 16
#define NTIL (SEQ/KBLK)  // 32 tiles per bh
#define THR  11.5f       // defer-max threshold (log2 domain)
#define KPAT(r) ((((r)&3)) + 8*((r)>>2))   // 32x32 C/D row pattern
#define WS_NEEDED ((size_t)2 * 64 * SEQ * DH * 2)   // K+V bf16 images = 33.5 MB

typedef short bf16x8 __attribute__((ext_vector_type(8)));   // 8 bf16 bits = 4 VGPRs
typedef float f32x16 __attribute__((ext_vector_type(16)));

union V4U { unsigned int w[4]; bf16x8 v; };

__device__ __forceinline__ short bfbits(float f) {
    unsigned int u = __float_as_uint(f);
    u += 0x7fff + ((u >> 16) & 1);
    return (short)(u >> 16);
}
__device__ __forceinline__ unsigned int cvtpk(float lo, float hi) {
    unsigned int r;
    asm("v_cvt_pk_bf16_f32 %0, %1, %2" : "=v"(r) : "v"(lo), "v"(hi));
    return r;
}
// swizzled short-index into a [rows][64] bf16 LDS tile (prep transpose only)
__device__ __forceinline__ int swz(int row, int col) {
    return row * 64 + (col ^ ((row & 7) << 3));
}

// ================= pre-pass: K/V -> bf16 FRAGMENT-MAJOR tile images =================
// K tile image layout (4096 shorts): idx = dc*1024 + h*512 + sub*256 + row32*8 + j
//   (fragment kf[dc], half h, k-sub-block sub, row within sub = lane ql)
// V tile image layout: idx = kt*1024 + h*512 + d*8 + j  (d = 0..63 output dim)
// -> every wave fragment load is 2x512B contiguous segments (fully coalesced).
__global__ __launch_bounds__(256) void prep_kv(const float* __restrict__ Kg,
                                               const float* __restrict__ Vg,
                                               short* __restrict__ Kimg,
                                               short* __restrict__ Vimg) {
    __shared__ __align__(16) short Vt[64 * 64];   // swizzled [d][k] transpose buffer
    const int tid = threadIdx.x;
    const int t   = blockIdx.x & (NTIL - 1);
    const int bh  = blockIdx.x / NTIL;
    const int kb  = t * KBLK;

    const float* Kb = Kg + (size_t)bh * SEQ * DH;
    const float* Vb = Vg + (size_t)bh * SEQ * DH;
    short* kim = Kimg + ((size_t)bh * NTIL + t) * 4096;
    short* vim = Vimg + ((size_t)bh * NTIL + t) * 4096;

    // ---- K: row kr, d-group dc -> fragment-major image ----
    {
        const int kr = tid >> 2, dc = tid & 3;        // kr 0..63, dc 0..3
        const float* src = Kb + (size_t)(kb + kr) * DH + dc * 16;
        const float4 a0 = *reinterpret_cast<const float4*>(src);
        const float4 a1 = *reinterpret_cast<const float4*>(src + 4);
        const float4 a2 = *reinterpret_cast<const float4*>(src + 8);
        const float4 a3 = *reinterpret_cast<const float4*>(src + 12);
        V4U u0, u1;                                   // h=0: j 0..7; h=1: j 8..15
        u0.w[0] = cvtpk(a0.x, a0.y); u0.w[1] = cvtpk(a0.z, a0.w);
        u0.w[2] = cvtpk(a1.x, a1.y); u0.w[3] = cvtpk(a1.z, a1.w);
        u1.w[0] = cvtpk(a2.x, a2.y); u1.w[1] = cvtpk(a2.z, a2.w);
        u1.w[2] = cvtpk(a3.x, a3.y); u1.w[3] = cvtpk(a3.z, a3.w);
        const int sub = kr >> 5, row = kr & 31;
        *reinterpret_cast<bf16x8*>(&kim[dc * 1024 +   0 + sub * 256 + row * 8]) = u0.v;
        *reinterpret_cast<bf16x8*>(&kim[dc * 1024 + 512 + sub * 256 + row * 8]) = u1.v;
    }
    // ---- V: transpose via LDS, then fragment-major copy-out ----
    {
        const int vk = tid & 63, vd0 = (tid >> 6) * 16;
        const float* src = Vb + (size_t)(kb + vk) * DH + vd0;
        const float4 b0 = *reinterpret_cast<const float4*>(src);
        const float4 b1 = *reinterpret_cast<const float4*>(src + 4);
        const float4 b2 = *reinterpret_cast<const float4*>(src + 8);
        const float4 b3 = *reinterpret_cast<const float4*>(src + 12);
        const float vv[16] = {b0.x,b0.y,b0.z,b0.w, b1.x,b1.y,b1.z,b1.w,
                              b2.x,b2.y,b2.z,b2.w, b3.x,b3.y,b3.z,b3.w};
        #pragma unroll
        for (int i = 0; i < 16; ++i)
            Vt[swz(vd0 + i, vk)] = bfbits(vv[i]);
    }
    __syncthreads();
    #pragma unroll
    for (int c = 0; c < 2; ++c) {
        const int flat  = tid * 16 + c * 8;           // short index in image
        const int combo = flat >> 9;                  // kt*2 + h
        const int d     = (flat >> 3) & 63;
        const int col   = (combo >> 1) * 16 + (combo & 1) * 8;
        *reinterpret_cast<bf16x8*>(&vim[flat]) =
            *reinterpret_cast<const bf16x8*>(&Vt[swz(d, col)]);
    }
}

// ================= compute helpers (global fragment loads, no LDS) =================
__device__ __forceinline__ void load_qfrags(const float* Qb, int q, int h, float SC,
                                            bf16x8 (&qb)[4]) {
    const float* qp = Qb + (size_t)q * DH + h * 8;
    #pragma unroll
    for (int dc = 0; dc < 4; ++dc) {
        const float4 a = *reinterpret_cast<const float4*>(qp + dc * 16);
        const float4 b = *reinterpret_cast<const float4*>(qp + dc * 16 + 4);
        V4U u;
        u.w[0] = cvtpk(a.x * SC, a.y * SC);
        u.w[1] = cvtpk(a.z * SC, a.w * SC);
        u.w[2] = cvtpk(b.x * SC, b.y * SC);
        u.w[3] = cvtpk(b.z * SC, b.w * SC);
        qb[dc] = u.v;
    }
}

// QK^T for one 32-row k-sub-block from the fragment-major K image
__device__ __forceinline__ f32x16 qk32g(const short* __restrict__ kt_, int sub, int ql, int h,
                                        const bf16x8 (&qb)[4]) {
    f32x16 s;
    #pragma unroll
    for (int i = 0; i < 16; ++i) s[i] = 0.f;
    bf16x8 kf[4];
    #pragma unroll
    for (int dc = 0; dc < 4; ++dc)
        kf[dc] = *reinterpret_cast<const bf16x8*>(&kt_[dc * 1024 + h * 512 + sub * 256 + ql * 8]);
    __builtin_amdgcn_s_setprio(1);
    #pragma unroll
    for (int dc = 0; dc < 4; ++dc)
        s = __builtin_amdgcn_mfma_f32_32x32x16_bf16(kf[dc], qb[dc], s, 0, 0, 0);
    __builtin_amdgcn_s_setprio(0);
    return s;
}

// mask + defer-max + exp(in-place) + pack into PV A-frags (R11's proven version)
__device__ __forceinline__ void sm_pack(f32x16& s0, f32x16& s1, bool v2,
                                        int kb, int qw, int q, int h,
                                        float& m, float& lsum,
                                        f32x16& o0, f32x16& o1, bf16x8 (&pa)[4]) {
    if (kb + 31 > qw) {
        #pragma unroll
        for (int r = 0; r < 16; ++r)
            if (kb + KPAT(r) + 4 * h > q) s0[r] = -1e30f;
    }
    if (v2 && (kb + 63 > qw)) {
        #pragma unroll
        for (int r = 0; r < 16; ++r)
            if (kb + 32 + KPAT(r) + 4 * h > q) s1[r] = -1e30f;
    }
    float mx = s0[0];
    #pragma unroll
    for (int r = 1; r < 16; ++r) mx = fmaxf(mx, s0[r]);
    if (v2) {
        #pragma unroll
        for (int r = 0; r < 16; ++r) mx = fmaxf(mx, s1[r]);
    }
    if (!__all(mx <= m + THR)) {
        mx = fmaxf(mx, __shfl_xor(mx, 32));
        const float mn  = fmaxf(m, mx);
        const float scl = __builtin_amdgcn_exp2f(m - mn);
        m = mn;
        lsum *= scl;
        #pragma unroll
        for (int r = 0; r < 16; ++r) {
            const float sr = __shfl(scl, KPAT(r) + 4 * h);
            o0[r] *= sr; o1[r] *= sr;
        }
    }
    #pragma unroll
    for (int r = 0; r < 16; ++r) { s0[r] = __builtin_amdgcn_exp2f(s0[r] - m); lsum += s0[r]; }
    #pragma unroll
    for (int oct = 0; oct < 2; ++oct) {
        const unsigned int A0 = cvtpk(s0[oct*8+0], s0[oct*8+1]);
        const unsigned int A1 = cvtpk(s0[oct*8+2], s0[oct*8+3]);
        const unsigned int B0 = cvtpk(s0[oct*8+4], s0[oct*8+5]);
        const unsigned int B1 = cvtpk(s0[oct*8+6], s0[oct*8+7]);
        const unsigned int t0 = h ? A0 : B0, t1 = h ? A1 : B1;
        const unsigned int r0 = (unsigned int)__shfl_xor((int)t0, 32);
        const unsigned int r1 = (unsigned int)__shfl_xor((int)t1, 32);
        V4U u;
        u.w[0] = h ? r0 : A0; u.w[1] = h ? r1 : A1;
        u.w[2] = h ? B0 : r0; u.w[3] = h ? B1 : r1;
        pa[oct] = u.v;
    }
    if (v2) {
        #pragma unroll
        for (int r = 0; r < 16; ++r) { s1[r] = __builtin_amdgcn_exp2f(s1[r] - m); lsum += s1[r]; }
        #pragma unroll
        for (int oct = 0; oct < 2; ++oct) {
            const unsigned int A0 = cvtpk(s1[oct*8+0], s1[oct*8+1]);
            const unsigned int A1 = cvtpk(s1[oct*8+2], s1[oct*8+3]);
            const unsigned int B0 = cvtpk(s1[oct*8+4], s1[oct*8+5]);
            const unsigned int B1 = cvtpk(s1[oct*8+6], s1[oct*8+7]);
            const unsigned int t0 = h ? A0 : B0, t1 = h ? A1 : B1;
            const unsigned int r0 = (unsigned int)__shfl_xor((int)t0, 32);
            const unsigned int r1 = (unsigned int)__shfl_xor((int)t1, 32);
            V4U u;
            u.w[0] = h ? r0 : A0; u.w[1] = h ? r1 : A1;
            u.w[2] = h ? B0 : r0; u.w[3] = h ? B1 : r1;
            pa[2 + oct] = u.v;
        }
    }
}

__device__ __forceinline__ void epilogue_store(float* Ob, int qw, int h, int ql,
                                               const f32x16& o0, const f32x16& o1,
                                               float lsum) {
    lsum += __shfl_xor(lsum, 32);
    const float inv = 1.0f / lsum;
    #pragma unroll
    for (int r = 0; r < 16; ++r) {
        const float ir  = __shfl(inv, KPAT(r) + 4 * h);
        const size_t row = (size_t)(qw + KPAT(r) + 4 * h);
        Ob[row * DH + ql]      = o0[r] * ir;
        Ob[row * DH + 32 + ql] = o1[r] * ir;
    }
}

// ================= main kernel: 1 wave / block, no LDS, no barriers =================
__global__ __launch_bounds__(64, 3) void attn_fwd(const float* __restrict__ Qg,
                                                  const short* __restrict__ Kimg,
                                                  const short* __restrict__ Vimg,
                                                  float* __restrict__ Og) {
    const int lane = threadIdx.x;
    const int h    = lane >> 5;
    const int ql   = lane & 31;

    // longest-first: widx 0..3 -> qblk 15 (32 q-rows each wave)
    const int bh   = blockIdx.x & 63;
    const int widx = blockIdx.x >> 6;              // 0..63
    const int qblk = (NQB - 1) - (widx >> 2);
    const int w    = widx & 3;

    const float* Qb   = Qg + (size_t)bh * SEQ * DH;
    const short* kimg = Kimg + (size_t)bh * NTIL * 4096;
    const short* vimg = Vimg + (size_t)bh * NTIL * 4096;
    float*       Ob   = Og + (size_t)bh * SEQ * DH;

    const float SC = 0.125f * 1.44269504f;         // 1/sqrt(64) * log2(e)

    const int qw   = qblk * QBLK + w * 32;         // wave's 32 q-rows
    const int q    = qw + ql;
    const int kend = qw + 32;                      // causal limit (exclusive)
    const int nt   = (kend + KBLK - 1) / KBLK;     // exactly the tiles this wave needs

    bf16x8 qb[4];
    load_qfrags(Qb, q, h, SC, qb);

    f32x16 o0, o1;
    #pragma unroll
    for (int i = 0; i < 16; ++i) { o0[i] = 0.f; o1[i] = 0.f; }
    float m = -1e30f, lsum = 0.f;

    for (int t = 0; t < nt; ++t) {
        const int kb = t * KBLK;
        const bool v2 = (kb + 32 < kend);
        const short* kt_ = kimg + (size_t)t * 4096;
        const short* vt_ = vimg + (size_t)t * 4096;

        // QK^T from fragment-major K image (coalesced global loads)
        f32x16 s0 = qk32g(kt_, 0, ql, h, qb);
        f32x16 s1;
        if (v2) s1 = qk32g(kt_, 1, ql, h, qb);

        // V fragments issued BEFORE softmax -> latency hides under it
        bf16x8 vf[8];
        #pragma unroll
        for (int kt = 0; kt < 4; ++kt) {
            vf[kt]     = *reinterpret_cast<const bf16x8*>(&vt_[kt * 1024 + h * 512 +       ql * 8]);
            vf[4 + kt] = *reinterpret_cast<const bf16x8*>(&vt_[kt * 1024 + h * 512 + 256 + ql * 8]);
        }

        bf16x8 pa[4];
        sm_pack(s0, s1, v2, kb, qw, q, h, m, lsum, o0, o1, pa);

        __builtin_amdgcn_s_setprio(1);
        #pragma unroll
        for (int kt = 0; kt < 2; ++kt) {
            o0 = __builtin_amdgcn_mfma_f32_32x32x16_bf16(pa[kt], vf[kt],     o0, 0, 0, 0);
            o1 = __builtin_amdgcn_mfma_f32_32x32x16_bf16(pa[kt], vf[4 + kt], o1, 0, 0, 0);
        }
        if (v2) {
            #pragma unroll
            for (int kt = 2; kt < 4; ++kt) {
                o0 = __builtin_amdgcn_mfma_f32_32x32x16_bf16(pa[kt], vf[kt],     o0, 0, 0, 0);
                o1 = __builtin_amdgcn_mfma_f32_32x32x16_bf16(pa[kt], vf[4 + kt], o1, 0, 0, 0);
            }
        }
        __builtin_amdgcn_s_setprio(0);
    }

    epilogue_store(Ob, qw, h, ql, o0, o1, lsum);
}

// ================= fallback (self-contained, used if ws too small) =================
__global__ __launch_bounds__(256) void attn_fwd_fb(const float* __restrict__ Qg,
                                                   const float* __restrict__ Kg,
                                                   const float* __restrict__ Vg,
                                                   float* __restrict__ Og) {
    // simple reg-staged LDS version (R6 lineage), correctness fallback only
    __shared__ __align__(16) short Ks[64 * 64];
    __shared__ __align__(16) short Vt[64 * 64];

    const int tid  = threadIdx.x;
    const int w    = tid >> 6;
    const int lane = tid & 63;
    const int h    = lane >> 5;
    const int ql   = lane & 31;

    const int qblk = blockIdx.x & (NQB - 1);
    const int bh   = blockIdx.x / NQB;
    const int q0   = qblk * QBLK;
    const int qw   = q0 + w * 32;
    const int q    = qw + ql;

    const float* Qb = Qg + (size_t)bh * SEQ * DH;
    const float* Kb = Kg + (size_t)bh * SEQ * DH;
    const float* Vb = Vg + (size_t)bh * SEQ * DH;
    float*       Ob = Og + (size_t)bh * SEQ * DH;

    const float SC = 0.125f * 1.44269504f;

    const int skr  = tid >> 2;
    const int sd0  = (tid & 3) * 16;
    const int svk  = tid & 63;
    const int svd0 = (tid >> 6) * 16;

    bf16x8 qb[4];
    load_qfrags(Qb, q, h, SC, qb);

    f32x16 o0, o1;
    #pragma unroll
    for (int i = 0; i < 16; ++i) { o0[i] = 0.f; o1[i] = 0.f; }
    float m = -1e30f, lsum = 0.f;

    const int kend = qw + 32;
    const int nt   = (q0 + QBLK) / KBLK;

    for (int t = 0; t < nt; ++t) {
        const int kb = t * KBLK;
        __syncthreads();
        {
            const float* src = Kb + (size_t)(kb + skr) * DH + sd0;
            const float4 a0 = *reinterpret_cast<const float4*>(src);
            const float4 a1 = *reinterpret_cast<const float4*>(src + 4);
            const float4 a2 = *reinterpret_cast<const float4*>(src + 8);
            const float4 a3 = *reinterpret_cast<const float4*>(src + 12);
            V4U u0, u1;
            u0.w[0] = cvtpk(a0.x, a0.y); u0.w[1] = cvtpk(a0.z, a0.w);
            u0.w[2] = cvtpk(a1.x, a1.y); u0.w[3] = cvtpk(a1.z, a1.w);
            u1.w[0] = cvtpk(a2.x, a2.y); u1.w[1] = cvtpk(a2.z, a2.w);
            u1.w[2] = cvtpk(a3.x, a3.y); u1.w[3] = cvtpk(a3.z, a3.w);
            *reinterpret_cast<bf16x8*>(&Ks[swz(skr, sd0)])     = u0.v;
            *reinterpret_cast<bf16x8*>(&Ks[swz(skr, sd0 + 8)]) = u1.v;

            const float* vsrc = Vb + (size_t)(kb + svk) * DH + svd0;
            const float4 b0 = *reinterpret_cast<const float4*>(vsrc);
            const float4 b1 = *reinterpret_cast<const float4*>(vsrc + 4);
            const float4 b2 = *reinterpret_cast<const float4*>(vsrc + 8);
            const float4 b3 = *reinterpret_cast<const float4*>(vsrc + 12);
            const float vv[16] = {b0.x,b0.y,b0.z,b0.w, b1.x,b1.y,b1.z,b1.w,
                                  b2.x,b2.y,b2.z,b2.w, b3.x,b3.y,b3.z,b3.w};
            #pragma unroll
            for (int i = 0; i < 16; ++i)
                Vt[swz(svd0 + i, svk)] = bfbits(vv[i]);
        }
        __syncthreads();

        if (kb < kend) {
            const bool v2 = (kb + 32 < kend);
            f32x16 s0, s1;
            {
                bf16x8 kf[4];
                #pragma unroll
                for (int i = 0; i < 16; ++i) s0[i] = 0.f;
                #pragma unroll
                for (int dc = 0; dc < 4; ++dc)
                    kf[dc] = *reinterpret_cast<const bf16x8*>(&Ks[swz(ql, dc * 16 + h * 8)]);
                #pragma unroll
                for (int dc = 0; dc < 4; ++dc)
                    s0 = __builtin_amdgcn_mfma_f32_32x32x16_bf16(kf[dc], qb[dc], s0, 0, 0, 0);
                if (v2) {
                    #pragma unroll
                    for (int i = 0; i < 16; ++i) s1[i] = 0.f;
                    #pragma unroll
                    for (int dc = 0; dc < 4; ++dc)
                        kf[dc] = *reinterpret_cast<const bf16x8*>(&Ks[swz(32 + ql, dc * 16 + h * 8)]);
                    #pragma unroll
                    for (int dc = 0; dc < 4; ++dc)
                        s1 = __builtin_amdgcn_mfma_f32_32x32x16_bf16(kf[dc], qb[dc], s1, 0, 0, 0);
                }
            }
            bf16x8 pa[4];
            sm_pack(s0, s1, v2, kb, qw, q, h, m, lsum, o0, o1, pa);
            #pragma unroll
            for (int kt = 0; kt < 2; ++kt) {
                const bf16x8 vb0 = *reinterpret_cast<const bf16x8*>(&Vt[swz(ql,      kt * 16 + h * 8)]);
                const bf16x8 vb1 = *reinterpret_cast<const bf16x8*>(&Vt[swz(32 + ql, kt * 16 + h * 8)]);
                o0 = __builtin_amdgcn_mfma_f32_32x32x16_bf16(pa[kt], vb0, o0, 0, 0, 0);
                o1 = __builtin_amdgcn_mfma_f32_32x32x16_bf16(pa[kt], vb1, o1, 0, 0, 0);
            }
            if (v2) {
                #pragma unroll
                for (int kt = 2; kt < 4; ++kt) {
                    const bf16x8 vb0 = *reinterpret_cast<const bf16x8*>(&Vt[swz(ql,      kt * 16 + h * 8)]);
                    const bf16x8 vb1 = *reinterpret_cast<const bf16x8*>(&Vt[swz(32 + ql, kt * 16 + h * 8)]);
                    o0 = __builtin_amdgcn_mfma_f32_32x32x16_bf16(pa[kt], vb0, o0, 0, 0, 0);
                    o1 = __builtin_amdgcn_mfma_f32_32x32x16_bf16(pa[kt], vb1, o1, 0, 0, 0);
                }
            }
        }
    }

    epilogue_store(Ob, qw, h, ql, o0, o1, lsum);
}

extern "C" void kernel_launch(void* const* d_in, const int* in_sizes, int n_in,
                              void* d_out, int out_size, void* d_ws, size_t ws_size,
                              hipStream_t stream) {
    const float* Q = (const float*)d_in[0];
    const float* K = (const float*)d_in[1];
    const float* V = (const float*)d_in[2];
    // d_in[3] causal mask: synthesized in-kernel, not read.
    float* O = (float*)d_out;

    if (ws_size >= WS_NEEDED) {
        short* Kimg = (short*)d_ws;
        short* Vimg = Kimg + (size_t)64 * NTIL * 4096;
        prep_kv<<<dim3(64 * NTIL), 256, 0, stream>>>(K, V, Kimg, Vimg);
        attn_fwd<<<dim3(64 * 64), 64, 0, stream>>>(Q, Kimg, Vimg, O);
    } else {
        attn_fwd_fb<<<dim3(64 * NQB), 256, 0, stream>>>(Q, K, V, O);
    }
}

// Round 15
// 79.089 us; speedup vs baseline: 1.4678x; 1.0038x over previous
//
#include <hip/hip_runtime.h>

#define SEQ  2048
#define DH   64
#define QBLK 128         // q rows per q-block
#define KBLK 64          // k/v rows per tile
#define NQB  (SEQ/QBLK)  // 16
#define NTIL (SEQ/KBLK)  // 32 tiles per bh
#define THR  11.5f       // defer-max threshold (log2 domain)
#define KPAT(r) ((((r)&3)) + 8*((r)>>2))   // 32x32 C/D row pattern
#define WS_NEEDED ((size_t)2 * 64 * SEQ * DH * 2)   // K+V bf16 images = 33.5 MB

typedef short bf16x8 __attribute__((ext_vector_type(8)));   // 8 bf16 bits = 4 VGPRs
typedef float f32x16 __attribute__((ext_vector_type(16)));

union V4U { unsigned int w[4]; bf16x8 v; };

__device__ __forceinline__ short bfbits(float f) {
    unsigned int u = __float_as_uint(f);
    u += 0x7fff + ((u >> 16) & 1);
    return (short)(u >> 16);
}
__device__ __forceinline__ unsigned int cvtpk(float lo, float hi) {
    unsigned int r;
    asm("v_cvt_pk_bf16_f32 %0, %1, %2" : "=v"(r) : "v"(lo), "v"(hi));
    return r;
}
// swizzled short-index into a [rows][64] bf16 LDS tile (prep transpose only)
__device__ __forceinline__ int swz(int row, int col) {
    return row * 64 + (col ^ ((row & 7) << 3));
}

// ================= pre-pass: K/V -> bf16 FRAGMENT-MAJOR tile images =================
// K tile image layout (4096 shorts): idx = dc*1024 + h*512 + sub*256 + row32*8 + j
// V tile image layout: idx = kt*1024 + h*512 + d*8 + j  (d = 0..63 output dim)
// -> every wave fragment load is 512B contiguous segments (fully coalesced).
__global__ __launch_bounds__(256) void prep_kv(const float* __restrict__ Kg,
                                               const float* __restrict__ Vg,
                                               short* __restrict__ Kimg,
                                               short* __restrict__ Vimg) {
    __shared__ __align__(16) short Vt[64 * 64];   // swizzled [d][k] transpose buffer
    const int tid = threadIdx.x;
    const int t   = blockIdx.x & (NTIL - 1);
    const int bh  = blockIdx.x / NTIL;
    const int kb  = t * KBLK;

    const float* Kb = Kg + (size_t)bh * SEQ * DH;
    const float* Vb = Vg + (size_t)bh * SEQ * DH;
    short* kim = Kimg + ((size_t)bh * NTIL + t) * 4096;
    short* vim = Vimg + ((size_t)bh * NTIL + t) * 4096;

    // ---- K: row kr, d-group dc -> fragment-major image ----
    {
        const int kr = tid >> 2, dc = tid & 3;        // kr 0..63, dc 0..3
        const float* src = Kb + (size_t)(kb + kr) * DH + dc * 16;
        const float4 a0 = *reinterpret_cast<const float4*>(src);
        const float4 a1 = *reinterpret_cast<const float4*>(src + 4);
        const float4 a2 = *reinterpret_cast<const float4*>(src + 8);
        const float4 a3 = *reinterpret_cast<const float4*>(src + 12);
        V4U u0, u1;                                   // h=0: j 0..7; h=1: j 8..15
        u0.w[0] = cvtpk(a0.x, a0.y); u0.w[1] = cvtpk(a0.z, a0.w);
        u0.w[2] = cvtpk(a1.x, a1.y); u0.w[3] = cvtpk(a1.z, a1.w);
        u1.w[0] = cvtpk(a2.x, a2.y); u1.w[1] = cvtpk(a2.z, a2.w);
        u1.w[2] = cvtpk(a3.x, a3.y); u1.w[3] = cvtpk(a3.z, a3.w);
        const int sub = kr >> 5, row = kr & 31;
        *reinterpret_cast<bf16x8*>(&kim[dc * 1024 +   0 + sub * 256 + row * 8]) = u0.v;
        *reinterpret_cast<bf16x8*>(&kim[dc * 1024 + 512 + sub * 256 + row * 8]) = u1.v;
    }
    // ---- V: transpose via LDS, then fragment-major copy-out ----
    {
        const int vk = tid & 63, vd0 = (tid >> 6) * 16;
        const float* src = Vb + (size_t)(kb + vk) * DH + vd0;
        const float4 b0 = *reinterpret_cast<const float4*>(src);
        const float4 b1 = *reinterpret_cast<const float4*>(src + 4);
        const float4 b2 = *reinterpret_cast<const float4*>(src + 8);
        const float4 b3 = *reinterpret_cast<const float4*>(src + 12);
        const float vv[16] = {b0.x,b0.y,b0.z,b0.w, b1.x,b1.y,b1.z,b1.w,
                              b2.x,b2.y,b2.z,b2.w, b3.x,b3.y,b3.z,b3.w};
        #pragma unroll
        for (int i = 0; i < 16; ++i)
            Vt[swz(vd0 + i, vk)] = bfbits(vv[i]);
    }
    __syncthreads();
    #pragma unroll
    for (int c = 0; c < 2; ++c) {
        const int flat  = tid * 16 + c * 8;           // short index in image
        const int combo = flat >> 9;                  // kt*2 + h
        const int d     = (flat >> 3) & 63;
        const int col   = (combo >> 1) * 16 + (combo & 1) * 8;
        *reinterpret_cast<bf16x8*>(&vim[flat]) =
            *reinterpret_cast<const bf16x8*>(&Vt[swz(d, col)]);
    }
}

// ================= compute helpers (global fragment loads, no LDS) =================
__device__ __forceinline__ void load_qfrags(const float* Qb, int q, int h, float SC,
                                            bf16x8 (&qb)[4]) {
    const float* qp = Qb + (size_t)q * DH + h * 8;
    #pragma unroll
    for (int dc = 0; dc < 4; ++dc) {
        const float4 a = *reinterpret_cast<const float4*>(qp + dc * 16);
        const float4 b = *reinterpret_cast<const float4*>(qp + dc * 16 + 4);
        V4U u;
        u.w[0] = cvtpk(a.x * SC, a.y * SC);
        u.w[1] = cvtpk(a.z * SC, a.w * SC);
        u.w[2] = cvtpk(b.x * SC, b.y * SC);
        u.w[3] = cvtpk(b.z * SC, b.w * SC);
        qb[dc] = u.v;
    }
}

// QK^T for one 32-row k-sub-block from the fragment-major K image
__device__ __forceinline__ f32x16 qk32g(const short* __restrict__ kt_, int sub, int ql, int h,
                                        const bf16x8 (&qb)[4]) {
    f32x16 s;
    #pragma unroll
    for (int i = 0; i < 16; ++i) s[i] = 0.f;
    bf16x8 kf[4];
    #pragma unroll
    for (int dc = 0; dc < 4; ++dc)
        kf[dc] = *reinterpret_cast<const bf16x8*>(&kt_[dc * 1024 + h * 512 + sub * 256 + ql * 8]);
    __builtin_amdgcn_s_setprio(1);
    #pragma unroll
    for (int dc = 0; dc < 4; ++dc)
        s = __builtin_amdgcn_mfma_f32_32x32x16_bf16(kf[dc], qb[dc], s, 0, 0, 0);
    __builtin_amdgcn_s_setprio(0);
    return s;
}

// mask + defer-max + exp(in-place) + pack into PV A-frags
__device__ __forceinline__ void sm_pack(f32x16& s0, f32x16& s1, bool v2,
                                        int kb, int qw, int q, int h,
                                        float& m, float& lsum,
                                        f32x16& o0, f32x16& o1, bf16x8 (&pa)[4]) {
    if (kb + 31 > qw) {
        #pragma unroll
        for (int r = 0; r < 16; ++r)
            if (kb + KPAT(r) + 4 * h > q) s0[r] = -1e30f;
    }
    if (v2 && (kb + 63 > qw)) {
        #pragma unroll
        for (int r = 0; r < 16; ++r)
            if (kb + 32 + KPAT(r) + 4 * h > q) s1[r] = -1e30f;
    }
    float mx = s0[0];
    #pragma unroll
    for (int r = 1; r < 16; ++r) mx = fmaxf(mx, s0[r]);
    if (v2) {
        #pragma unroll
        for (int r = 0; r < 16; ++r) mx = fmaxf(mx, s1[r]);
    }
    if (!__all(mx <= m + THR)) {
        mx = fmaxf(mx, __shfl_xor(mx, 32));
        const float mn  = fmaxf(m, mx);
        const float scl = __builtin_amdgcn_exp2f(m - mn);
        m = mn;
        lsum *= scl;
        #pragma unroll
        for (int r = 0; r < 16; ++r) {
            const float sr = __shfl(scl, KPAT(r) + 4 * h);
            o0[r] *= sr; o1[r] *= sr;
        }
    }
    #pragma unroll
    for (int r = 0; r < 16; ++r) { s0[r] = __builtin_amdgcn_exp2f(s0[r] - m); lsum += s0[r]; }
    #pragma unroll
    for (int oct = 0; oct < 2; ++oct) {
        const unsigned int A0 = cvtpk(s0[oct*8+0], s0[oct*8+1]);
        const unsigned int A1 = cvtpk(s0[oct*8+2], s0[oct*8+3]);
        const unsigned int B0 = cvtpk(s0[oct*8+4], s0[oct*8+5]);
        const unsigned int B1 = cvtpk(s0[oct*8+6], s0[oct*8+7]);
        const unsigned int t0 = h ? A0 : B0, t1 = h ? A1 : B1;
        const unsigned int r0 = (unsigned int)__shfl_xor((int)t0, 32);
        const unsigned int r1 = (unsigned int)__shfl_xor((int)t1, 32);
        V4U u;
        u.w[0] = h ? r0 : A0; u.w[1] = h ? r1 : A1;
        u.w[2] = h ? B0 : r0; u.w[3] = h ? B1 : r1;
        pa[oct] = u.v;
    }
    if (v2) {
        #pragma unroll
        for (int r = 0; r < 16; ++r) { s1[r] = __builtin_amdgcn_exp2f(s1[r] - m); lsum += s1[r]; }
        #pragma unroll
        for (int oct = 0; oct < 2; ++oct) {
            const unsigned int A0 = cvtpk(s1[oct*8+0], s1[oct*8+1]);
            const unsigned int A1 = cvtpk(s1[oct*8+2], s1[oct*8+3]);
            const unsigned int B0 = cvtpk(s1[oct*8+4], s1[oct*8+5]);
            const unsigned int B1 = cvtpk(s1[oct*8+6], s1[oct*8+7]);
            const unsigned int t0 = h ? A0 : B0, t1 = h ? A1 : B1;
            const unsigned int r0 = (unsigned int)__shfl_xor((int)t0, 32);
            const unsigned int r1 = (unsigned int)__shfl_xor((int)t1, 32);
            V4U u;
            u.w[0] = h ? r0 : A0; u.w[1] = h ? r1 : A1;
            u.w[2] = h ? B0 : r0; u.w[3] = h ? B1 : r1;
            pa[2 + oct] = u.v;
        }
    }
}

__device__ __forceinline__ void epilogue_store(float* Ob, int qw, int h, int ql,
                                               const f32x16& o0, const f32x16& o1,
                                               float lsum) {
    lsum += __shfl_xor(lsum, 32);
    const float inv = 1.0f / lsum;
    #pragma unroll
    for (int r = 0; r < 16; ++r) {
        const float ir  = __shfl(inv, KPAT(r) + 4 * h);
        const size_t row = (size_t)(qw + KPAT(r) + 4 * h);
        Ob[row * DH + ql]      = o0[r] * ir;
        Ob[row * DH + 32 + ql] = o1[r] * ir;
    }
}

// ================= main kernel: 1 wave / block, no LDS, XCD-local bh mapping =================
__global__ __launch_bounds__(64, 3) void attn_fwd(const float* __restrict__ Qg,
                                                  const short* __restrict__ Kimg,
                                                  const short* __restrict__ Vimg,
                                                  float* __restrict__ Og) {
    const int lane = threadIdx.x;
    const int h    = lane >> 5;
    const int ql   = lane & 31;

    // XCD-locality swizzle: dispatcher assigns XCD ~ bid%8. Map each XCD to
    // an exclusive group of 8 bh's -> per-XCD K/V working set 33.5MB -> 4.2MB
    // (~L2-resident), so fragment re-reads hit the XCD's L2 instead of
    // streaming from Infinity Cache. widx ascending keeps longest-first.
    const int xcd  = blockIdx.x & 7;
    const int rest = blockIdx.x >> 3;
    const int bh   = xcd * 8 + (rest & 7);
    const int widx = rest >> 3;                    // 0..63
    const int qblk = (NQB - 1) - (widx >> 2);      // longest-first
    const int w    = widx & 3;

    const float* Qb   = Qg + (size_t)bh * SEQ * DH;
    const short* kimg = Kimg + (size_t)bh * NTIL * 4096;
    const short* vimg = Vimg + (size_t)bh * NTIL * 4096;
    float*       Ob   = Og + (size_t)bh * SEQ * DH;

    const float SC = 0.125f * 1.44269504f;         // 1/sqrt(64) * log2(e)

    const int qw   = qblk * QBLK + w * 32;         // wave's 32 q-rows
    const int q    = qw + ql;
    const int kend = qw + 32;                      // causal limit (exclusive)
    const int nt   = (kend + KBLK - 1) / KBLK;     // exactly the tiles this wave needs

    bf16x8 qb[4];
    load_qfrags(Qb, q, h, SC, qb);

    f32x16 o0, o1;
    #pragma unroll
    for (int i = 0; i < 16; ++i) { o0[i] = 0.f; o1[i] = 0.f; }
    float m = -1e30f, lsum = 0.f;

    for (int t = 0; t < nt; ++t) {
        const int kb = t * KBLK;
        const bool v2 = (kb + 32 < kend);
        const short* kt_ = kimg + (size_t)t * 4096;
        const short* vt_ = vimg + (size_t)t * 4096;

        // QK^T from fragment-major K image (coalesced global loads)
        f32x16 s0 = qk32g(kt_, 0, ql, h, qb);
        f32x16 s1;
        if (v2) s1 = qk32g(kt_, 1, ql, h, qb);

        // V fragments issued BEFORE softmax -> latency hides under it
        bf16x8 vf[8];
        #pragma unroll
        for (int kt = 0; kt < 4; ++kt) {
            vf[kt]     = *reinterpret_cast<const bf16x8*>(&vt_[kt * 1024 + h * 512 +       ql * 8]);
            vf[4 + kt] = *reinterpret_cast<const bf16x8*>(&vt_[kt * 1024 + h * 512 + 256 + ql * 8]);
        }

        bf16x8 pa[4];
        sm_pack(s0, s1, v2, kb, qw, q, h, m, lsum, o0, o1, pa);

        __builtin_amdgcn_s_setprio(1);
        #pragma unroll
        for (int kt = 0; kt < 2; ++kt) {
            o0 = __builtin_amdgcn_mfma_f32_32x32x16_bf16(pa[kt], vf[kt],     o0, 0, 0, 0);
            o1 = __builtin_amdgcn_mfma_f32_32x32x16_bf16(pa[kt], vf[4 + kt], o1, 0, 0, 0);
        }
        if (v2) {
            #pragma unroll
            for (int kt = 2; kt < 4; ++kt) {
                o0 = __builtin_amdgcn_mfma_f32_32x32x16_bf16(pa[kt], vf[kt],     o0, 0, 0, 0);
                o1 = __builtin_amdgcn_mfma_f32_32x32x16_bf16(pa[kt], vf[4 + kt], o1, 0, 0, 0);
            }
        }
        __builtin_amdgcn_s_setprio(0);
    }

    epilogue_store(Ob, qw, h, ql, o0, o1, lsum);
}

// ================= fallback (self-contained, used if ws too small) =================
__global__ __launch_bounds__(256) void attn_fwd_fb(const float* __restrict__ Qg,
                                                   const float* __restrict__ Kg,
                                                   const float* __restrict__ Vg,
                                                   float* __restrict__ Og) {
    __shared__ __align__(16) short Ks[64 * 64];
    __shared__ __align__(16) short Vt[64 * 64];

    const int tid  = threadIdx.x;
    const int w    = tid >> 6;
    const int lane = tid & 63;
    const int h    = lane >> 5;
    const int ql   = lane & 31;

    const int qblk = blockIdx.x & (NQB - 1);
    const int bh   = blockIdx.x / NQB;
    const int q0   = qblk * QBLK;
    const int qw   = q0 + w * 32;
    const int q    = qw + ql;

    const float* Qb = Qg + (size_t)bh * SEQ * DH;
    const float* Kb = Kg + (size_t)bh * SEQ * DH;
    const float* Vb = Vg + (size_t)bh * SEQ * DH;
    float*       Ob = Og + (size_t)bh * SEQ * DH;

    const float SC = 0.125f * 1.44269504f;

    const int skr  = tid >> 2;
    const int sd0  = (tid & 3) * 16;
    const int svk  = tid & 63;
    const int svd0 = (tid >> 6) * 16;

    bf16x8 qb[4];
    load_qfrags(Qb, q, h, SC, qb);

    f32x16 o0, o1;
    #pragma unroll
    for (int i = 0; i < 16; ++i) { o0[i] = 0.f; o1[i] = 0.f; }
    float m = -1e30f, lsum = 0.f;

    const int kend = qw + 32;
    const int nt   = (q0 + QBLK) / KBLK;

    for (int t = 0; t < nt; ++t) {
        const int kb = t * KBLK;
        __syncthreads();
        {
            const float* src = Kb + (size_t)(kb + skr) * DH + sd0;
            const float4 a0 = *reinterpret_cast<const float4*>(src);
            const float4 a1 = *reinterpret_cast<const float4*>(src + 4);
            const float4 a2 = *reinterpret_cast<const float4*>(src + 8);
            const float4 a3 = *reinterpret_cast<const float4*>(src + 12);
            V4U u0, u1;
            u0.w[0] = cvtpk(a0.x, a0.y); u0.w[1] = cvtpk(a0.z, a0.w);
            u0.w[2] = cvtpk(a1.x, a1.y); u0.w[3] = cvtpk(a1.z, a1.w);
            u1.w[0] = cvtpk(a2.x, a2.y); u1.w[1] = cvtpk(a2.z, a2.w);
            u1.w[2] = cvtpk(a3.x, a3.y); u1.w[3] = cvtpk(a3.z, a3.w);
            *reinterpret_cast<bf16x8*>(&Ks[swz(skr, sd0)])     = u0.v;
            *reinterpret_cast<bf16x8*>(&Ks[swz(skr, sd0 + 8)]) = u1.v;

            const float* vsrc = Vb + (size_t)(kb + svk) * DH + svd0;
            const float4 b0 = *reinterpret_cast<const float4*>(vsrc);
            const float4 b1 = *reinterpret_cast<const float4*>(vsrc + 4);
            const float4 b2 = *reinterpret_cast<const float4*>(vsrc + 8);
            const float4 b3 = *reinterpret_cast<const float4*>(vsrc + 12);
            const float vv[16] = {b0.x,b0.y,b0.z,b0.w, b1.x,b1.y,b1.z,b1.w,
                                  b2.x,b2.y,b2.z,b2.w, b3.x,b3.y,b3.z,b3.w};
            #pragma unroll
            for (int i = 0; i < 16; ++i)
                Vt[swz(svd0 + i, svk)] = bfbits(vv[i]);
        }
        __syncthreads();

        if (kb < kend) {
            const bool v2 = (kb + 32 < kend);
            f32x16 s0, s1;
            {
                bf16x8 kf[4];
                #pragma unroll
                for (int i = 0; i < 16; ++i) s0[i] = 0.f;
                #pragma unroll
                for (int dc = 0; dc < 4; ++dc)
                    kf[dc] = *reinterpret_cast<const bf16x8*>(&Ks[swz(ql, dc * 16 + h * 8)]);
                #pragma unroll
                for (int dc = 0; dc < 4; ++dc)
                    s0 = __builtin_amdgcn_mfma_f32_32x32x16_bf16(kf[dc], qb[dc], s0, 0, 0, 0);
                if (v2) {
                    #pragma unroll
                    for (int i = 0; i < 16; ++i) s1[i] = 0.f;
                    #pragma unroll
                    for (int dc = 0; dc < 4; ++dc)
                        kf[dc] = *reinterpret_cast<const bf16x8*>(&Ks[swz(32 + ql, dc * 16 + h * 8)]);
                    #pragma unroll
                    for (int dc = 0; dc < 4; ++dc)
                        s1 = __builtin_amdgcn_mfma_f32_32x32x16_bf16(kf[dc], qb[dc], s1, 0, 0, 0);
                }
            }
            bf16x8 pa[4];
            sm_pack(s0, s1, v2, kb, qw, q, h, m, lsum, o0, o1, pa);
            #pragma unroll
            for (int kt = 0; kt < 2; ++kt) {
                const bf16x8 vb0 = *reinterpret_cast<const bf16x8*>(&Vt[swz(ql,      kt * 16 + h * 8)]);
                const bf16x8 vb1 = *reinterpret_cast<const bf16x8*>(&Vt[swz(32 + ql, kt * 16 + h * 8)]);
                o0 = __builtin_amdgcn_mfma_f32_32x32x16_bf16(pa[kt], vb0, o0, 0, 0, 0);
                o1 = __builtin_amdgcn_mfma_f32_32x32x16_bf16(pa[kt], vb1, o1, 0, 0, 0);
            }
            if (v2) {
                #pragma unroll
                for (int kt = 2; kt < 4; ++kt) {
                    const bf16x8 vb0 = *reinterpret_cast<const bf16x8*>(&Vt[swz(ql,      kt * 16 + h * 8)]);
                    const bf16x8 vb1 = *reinterpret_cast<const bf16x8*>(&Vt[swz(32 + ql, kt * 16 + h * 8)]);
                    o0 = __builtin_amdgcn_mfma_f32_32x32x16_bf16(pa[kt], vb0, o0, 0, 0, 0);
                    o1 = __builtin_amdgcn_mfma_f32_32x32x16_bf16(pa[kt], vb1, o1, 0, 0, 0);
                }
            }
        }
    }

    epilogue_store(Ob, qw, h, ql, o0, o1, lsum);
}

extern "C" void kernel_launch(void* const* d_in, const int* in_sizes, int n_in,
                              void* d_out, int out_size, void* d_ws, size_t ws_size,
                              hipStream_t stream) {
    const float* Q = (const float*)d_in[0];
    const float* K = (const float*)d_in[1];
    const float* V = (const float*)d_in[2];
    // d_in[3] causal mask: synthesized in-kernel, not read.
    float* O = (float*)d_out;

    if (ws_size >= WS_NEEDED) {
        short* Kimg = (short*)d_ws;
        short* Vimg = Kimg + (size_t)64 * NTIL * 4096;
        prep_kv<<<dim3(64 * NTIL), 256, 0, stream>>>(K, V, Kimg, Vimg);
        attn_fwd<<<dim3(64 * 64), 64, 0, stream>>>(Q, Kimg, Vimg, O);
    } else {
        attn_fwd_fb<<<dim3(64 * NQB), 256, 0, stream>>>(Q, K, V, O);
    }
}